// Round 15
// baseline (299.260 us; speedup 1.0000x reference)
//
#include <hip/hip_runtime.h>
#include <stdint.h>

#define Hh   32
#define Ss   2048
#define Dd   2048
#define DHd  64
#define Mtok 4096   // B*S
#define MiB  (1u << 20)
#define NTK  32     // K tiles of 64 in Dd

typedef unsigned short u16;
typedef u16   u16x4  __attribute__((ext_vector_type(4)));
typedef u16   u16x8  __attribute__((ext_vector_type(8)));
typedef short bf16x8 __attribute__((ext_vector_type(8)));
typedef float f32x4  __attribute__((ext_vector_type(4)));

__device__ __forceinline__ u16 f2bf(float f) {
    union { float f; uint32_t u; } v; v.f = f;
    uint32_t r = v.u + 0x7fffu + ((v.u >> 16) & 1u);   // RNE
    return (u16)(r >> 16);
}
__device__ __forceinline__ uint32_t cvtpk_bf16(float lo, float hi) {
    uint32_t r;
    asm volatile("v_cvt_pk_bf16_f32 %0, %1, %2" : "=v"(r) : "v"(lo), "v"(hi));
    return r;
}
__device__ __forceinline__ void gld_lds16(const void* g, void* l) {
    __builtin_amdgcn_global_load_lds(
        (const __attribute__((address_space(1))) uint32_t*)g,
        (__attribute__((address_space(3))) uint32_t*)l,
        16, 0, 0);
}
#define SB() __builtin_amdgcn_sched_barrier(0)

// ---------------- fused fp32 -> bf16 convert (X + 4 weights, one launch) ----------------
__global__ void cvt_all(const float* __restrict__ x,  const float* __restrict__ qw,
                        const float* __restrict__ kw, const float* __restrict__ vw,
                        const float* __restrict__ ow,
                        u16* __restrict__ Xb, u16* __restrict__ Wcat, u16* __restrict__ Wob)
{
    const size_t nX = 1u << 23, nW = 1u << 22;
    size_t i = ((size_t)blockIdx.x * 256 + threadIdx.x) * 8;
    const float* src; u16* dst; size_t off;
    if (i < nX) { src = x; dst = Xb; off = i; }
    else {
        size_t j = i - nX;
        int seg = (int)(j >> 22);
        off = j & (nW - 1);
        src = (seg == 0) ? qw : (seg == 1) ? kw : (seg == 2) ? vw : ow;
        dst = (seg == 3) ? Wob : Wcat + (size_t)seg * nW;
    }
    f32x4 a = *(const f32x4*)(src + off);
    f32x4 b = *(const f32x4*)(src + off + 4);
    u16x8 o;
    o[0] = f2bf(a[0]); o[1] = f2bf(a[1]); o[2] = f2bf(a[2]); o[3] = f2bf(a[3]);
    o[4] = f2bf(b[0]); o[5] = f2bf(b[1]); o[6] = f2bf(b[2]); o[7] = f2bf(b[3]);
    *(u16x8*)(dst + off) = o;
}

// ================= shared staging / frag helpers =================
// Unit = 256 rows x 32 cols (or 128x32 for stage_unitA), row-pair XOR swizzle:
// 16B chunk c4 = ((row&1)<<2)|(col>>3), phys = c4 ^ ((row>>1)&7).
__device__ __forceinline__ void stage_unitA(const u16* __restrict__ src, u16* dst, int wid, int lane)
{   // 128 rows x 32 cols, 1 load/thread (8 waves)
    const int P = wid * 64 + lane;
    const int rp = P >> 3, c4p = P & 7, c4 = c4p ^ (rp & 7);
    const int r = rp * 2 + (c4 >> 2), c = (c4 & 3) * 8;
    gld_lds16(src + (size_t)r * Dd + c, dst + wid * 512);
}
__device__ __forceinline__ void stage_unitB(const u16* __restrict__ src, u16* dst, int wid, int lane)
{   // 256 rows x 32 cols, 2 loads/thread (8 waves)
#pragma unroll
    for (int j = 0; j < 2; ++j) {
        const int P = j * 512 + wid * 64 + lane;
        const int rp = P >> 3, c4p = P & 7, c4 = c4p ^ (rp & 7);
        const int r = rp * 2 + (c4 >> 2), c = (c4 & 3) * 8;
        gld_lds16(src + (size_t)r * Dd + c, dst + j * 4096 + wid * 512);
    }
}
// 16-wave pair stage: waves 0-7 carry the A unit (256x32 = 1024 chunks), waves 8-15
// the B unit. TWO gld_lds per thread (8 waves x 64 lanes x 2 x 16B = 16KB = one unit).
__device__ __forceinline__ void stage_pair16(const u16* __restrict__ Asrc, const u16* __restrict__ Bsrc,
                                             u16* Adst, u16* Bdst, int wid, int lane)
{
    const int uid = wid & 7;
    const u16* src = (wid < 8) ? Asrc : Bsrc;
    u16*       dst = (wid < 8) ? Adst : Bdst;
#pragma unroll
    for (int j = 0; j < 2; ++j) {
        const int P = j * 512 + uid * 64 + lane;
        const int rp = P >> 3, c4p = P & 7, c4 = c4p ^ (rp & 7);
        const int r = rp * 2 + (c4 >> 2), c = (c4 & 3) * 8;
        gld_lds16(src + (size_t)r * Dd + c, dst + j * 4096 + uid * 512);
    }
}
__device__ __forceinline__ bf16x8 frag_read(const u16* unit, int r, int lg)
{
    const int rp = r >> 1;
    const int c4 = ((r & 1) << 2) | lg;
    const int c4p = c4 ^ (rp & 7);
    return *(const bf16x8*)(unit + rp * 64 + c4p * 8);
}

// ================= r9 2-phase core (BM=128, BN=256, 8 waves), used by oproj =================
__device__ __forceinline__ void gemm2_core(const u16* __restrict__ Ab, const u16* __restrict__ Wb,
                                           u16* L, f32x4 acc[4][4],
                                           int wid, int lane, int l15, int lg, int wm, int wn)
{
    u16* const L0 = L;
    u16* const L1 = L + 24576;
    stage_unitA(Ab + 0,  L0 + 0,     wid, lane);
    stage_unitB(Wb + 0,  L0 + 8192,  wid, lane);
    stage_unitA(Ab + 32, L0 + 4096,  wid, lane);
    stage_unitB(Wb + 32, L0 + 16384, wid, lane);
    stage_unitA(Ab + 64, L1 + 0,     wid, lane);
    stage_unitB(Wb + 64, L1 + 8192,  wid, lane);
    asm volatile("s_waitcnt vmcnt(6)" ::: "memory");
    SB(); __builtin_amdgcn_s_barrier(); SB();

    const int aro = wm * 64 + l15;
    const int bro = wn * 64 + l15;
#pragma unroll 2
    for (int t = 0; t < NTK; ++t) {
        u16* const Lc = (t & 1) ? L1 : L0;
        u16* const Ln = (t & 1) ? L0 : L1;
#pragma unroll
        for (int ph = 0; ph < 2; ++ph) {
            const u16* Au = Lc + ph * 4096;
            const u16* Bu = Lc + 8192 + ph * 8192;
            bf16x8 bfr[4], a[4];
#pragma unroll
            for (int ni = 0; ni < 4; ++ni) bfr[ni] = frag_read(Bu, bro + ni * 16, lg);
#pragma unroll
            for (int mi = 0; mi < 4; ++mi) a[mi] = frag_read(Au, aro + mi * 16, lg);
            if (ph == 0) {
                if (t + 1 < NTK) {
                    stage_unitA(Ab + (t + 1) * 64 + 32, Ln + 4096,  wid, lane);
                    stage_unitB(Wb + (t + 1) * 64 + 32, Ln + 16384, wid, lane);
                }
            } else {
                if (t + 2 < NTK) {
                    stage_unitA(Ab + (t + 2) * 64, Lc + 0,    wid, lane);
                    stage_unitB(Wb + (t + 2) * 64, Lc + 8192, wid, lane);
                }
            }
            asm volatile("s_waitcnt lgkmcnt(0)" ::: "memory");
            SB();
            __builtin_amdgcn_s_setprio(1);
#pragma unroll
            for (int mi = 0; mi < 4; ++mi)
#pragma unroll
                for (int ni = 0; ni < 4; ++ni)
                    acc[mi][ni] = __builtin_amdgcn_mfma_f32_16x16x32_bf16(a[mi], bfr[ni], acc[mi][ni], 0, 0, 0);
            __builtin_amdgcn_s_setprio(0);
            const bool deep = (ph == 0) ? (t + 1 < NTK) : (t + 2 < NTK);
            if (deep) { asm volatile("s_waitcnt vmcnt(6)" ::: "memory"); }
            else      { asm volatile("s_waitcnt vmcnt(0)" ::: "memory"); }
            SB(); __builtin_amdgcn_s_barrier(); SB();
        }
    }
}

// ================= 256x256 core, 16 waves (wave tile 64x64, acc[4][4] -> no spill) =====
// LDS 128KB: 2 buf x {A0,A1,B0,B1} units of 256x32. Per SP: 8 ds_read + 2-load pair-stage
// + 16 MFMA + counted vmcnt(4) + ONE barrier. Queue (per wave, 2 loads/call):
// prologue 3 calls = 6 loads -> vmcnt(2) = tile0 landed; steady <=3 calls in flight ->
// vmcnt(4) = oldest call (the pair the NEXT SP reads) landed.
__device__ __forceinline__ void gemm256w16_core(const u16* __restrict__ Ab, const u16* __restrict__ Wb,
                                                u16* L, f32x4 acc[4][4],
                                                int wid, int lane, int l15, int lg, int wm, int wn)
{
    u16* const L0 = L;            // units (u16): A0 @0, A1 @8192, B0 @16384, B1 @24576
    u16* const L1 = L + 32768;
    stage_pair16(Ab + 0,  Wb + 0,  L0 + 0,    L0 + 16384, wid, lane);   // pair(0,ks0)
    stage_pair16(Ab + 32, Wb + 32, L0 + 8192, L0 + 24576, wid, lane);   // pair(0,ks1)
    stage_pair16(Ab + 64, Wb + 64, L1 + 0,    L1 + 16384, wid, lane);   // pair(1,ks0)
    asm volatile("s_waitcnt vmcnt(2)" ::: "memory");                    // tile0 landed
    SB(); __builtin_amdgcn_s_barrier(); SB();

    const int aro = wm * 64 + l15;
    const int bro = wn * 64 + l15;
#pragma unroll 2
    for (int t = 0; t < NTK; ++t) {
        u16* const Lc = (t & 1) ? L1 : L0;
        u16* const Ln = (t & 1) ? L0 : L1;
#pragma unroll
        for (int sp = 0; sp < 2; ++sp) {
            const u16* Au = Lc + sp * 8192;
            const u16* Bu = Lc + 16384 + sp * 8192;
            bf16x8 bfr[4], a[4];
#pragma unroll
            for (int ni = 0; ni < 4; ++ni) bfr[ni] = frag_read(Bu, bro + ni * 16, lg);
#pragma unroll
            for (int mi = 0; mi < 4; ++mi) a[mi] = frag_read(Au, aro + mi * 16, lg);
            // stage: sp0 -> pair(t+1,ks1) into Ln (regions last read at SP(t-1,sp1));
            //        sp1 -> pair(t+2,ks0) into Lc (regions read this tile at sp0)
            bool staged;
            if (sp == 0) {
                staged = (t + 1 < NTK);
                if (staged) stage_pair16(Ab + (t + 1) * 64 + 32, Wb + (t + 1) * 64 + 32,
                                         Ln + 8192, Ln + 24576, wid, lane);
            } else {
                staged = (t + 2 < NTK);
                if (staged) stage_pair16(Ab + (t + 2) * 64, Wb + (t + 2) * 64,
                                         Lc + 0, Lc + 16384, wid, lane);
            }
            asm volatile("s_waitcnt lgkmcnt(0)" ::: "memory");
            SB();
            __builtin_amdgcn_s_setprio(1);
#pragma unroll
            for (int mi = 0; mi < 4; ++mi)
#pragma unroll
                for (int ni = 0; ni < 4; ++ni)
                    acc[mi][ni] = __builtin_amdgcn_mfma_f32_16x16x32_bf16(a[mi], bfr[ni], acc[mi][ni], 0, 0, 0);
            __builtin_amdgcn_s_setprio(0);
            // counted wait: pair needed by the next SP is the oldest call of <=3 in flight
            if (staged) { asm volatile("s_waitcnt vmcnt(4)" ::: "memory"); }
            else        { asm volatile("s_waitcnt vmcnt(0)" ::: "memory"); }
            SB(); __builtin_amdgcn_s_barrier(); SB();
        }
    }
}

// ---------------- fused QKV projection (256^2, 16 waves) ----------------
__global__ __launch_bounds__(1024, 1) void gemm_qkv256(
    const u16* __restrict__ X, const u16* __restrict__ Wcat,
    const float* __restrict__ Bq, const float* __restrict__ Bk, const float* __restrict__ Bv,
    u16* __restrict__ Qo, u16* __restrict__ Ko, u16* __restrict__ Vo)
{
    __shared__ __align__(16) u16 L[2 * 32768];   // 128 KB
    const int tid = threadIdx.x, wid = tid >> 6, lane = tid & 63;
    const int l15 = lane & 15, lg = lane >> 4;
    const int wm = wid >> 2, wn = wid & 3;        // 4x4 waves, 64x64 tile each
    const int bid = blockIdx.x;                   // 384 blocks: XCD-bijective 8 x 48
    const int swz = (bid & 7) * 48 + (bid >> 3);
    const int m0 = (swz / 24) * 256, n0 = (swz % 24) * 256;

    f32x4 acc[4][4] = {};
    gemm256w16_core(X + (size_t)m0 * Dd, Wcat + (size_t)n0 * Dd, L, acc, wid, lane, l15, lg, wm, wn);

#pragma unroll
    for (int ni = 0; ni < 4; ++ni) {
        const int n = n0 + wn * 64 + ni * 16 + l15;
        const int z = n >> 11, nn = n & 2047;
        const float bv = (z == 0 ? Bq : z == 1 ? Bk : Bv)[nn];
        const float sc = (z == 0) ? 0.125f : 1.0f;
        u16* Out = (z == 0 ? Qo : z == 1 ? Ko : Vo);
        const int h = nn >> 6, dh = nn & 63;
#pragma unroll
        for (int mi = 0; mi < 4; ++mi)
#pragma unroll
            for (int r = 0; r < 4; ++r) {
                const int m = m0 + wm * 64 + mi * 16 + lg * 4 + r;
                const int b = m >> 11, s = m & 2047;
                Out[(((size_t)b * Hh + h) * Ss + s) * DHd + dh] = f2bf((acc[mi][ni][r] + bv) * sc);
            }
    }
}

// ---------------- output projection (r9 core, fp32 out) ----------------
__global__ __launch_bounds__(512) void gemm_oproj8(
    const u16* __restrict__ A, const u16* __restrict__ W,
    const float* __restrict__ Bi, float* __restrict__ Out)
{
    __shared__ __align__(16) u16 L[2 * 24576];   // 96 KB
    const int tid = threadIdx.x, wid = tid >> 6, lane = tid & 63;
    const int l15 = lane & 15, lg = lane >> 4;
    const int wm = wid >> 2, wn = wid & 3;
    const int m0 = blockIdx.x * 128, n0 = blockIdx.y * 256;

    f32x4 acc[4][4] = {};
    gemm2_core(A + (size_t)m0 * Dd, W + (size_t)n0 * Dd, L, acc, wid, lane, l15, lg, wm, wn);

#pragma unroll
    for (int ni = 0; ni < 4; ++ni) {
        const int n = n0 + wn * 64 + ni * 16 + l15;
        const float bv = Bi[n];
#pragma unroll
        for (int mi = 0; mi < 4; ++mi)
#pragma unroll
            for (int r = 0; r < 4; ++r) {
                const int m = m0 + wm * 64 + mi * 16 + lg * 4 + r;
                Out[(size_t)m * Dd + n] = acc[mi][ni][r] + bv;
            }
    }
}

// ---------------- V transpose: [BH][S][DH] -> [BH][DH][S] ----------------
__global__ void transpose_v(const u16* __restrict__ Vsrc, u16* __restrict__ Vdst)
{
    __shared__ __align__(16) u16 t[64 * 68];   // pad stride 68 elems
    const int bh = blockIdx.y, s0 = blockIdx.x * 64;
    const int tid = threadIdx.x;
    {
        const int r = tid >> 2, cq = (tid & 3) * 16;
        const u16* src = Vsrc + ((size_t)bh * Ss + s0 + r) * DHd;
#pragma unroll
        for (int j = 0; j < 4; ++j) {
            u16x4 v = *(const u16x4*)(src + cq + j * 4);
            *(u16x4*)&t[r * 68 + cq + j * 4] = v;
        }
    }
    __syncthreads();
    {
        const int d = tid >> 2, sq = (tid & 3) * 16;
        u16* dst = Vdst + ((size_t)bh * DHd + d) * Ss + s0;
#pragma unroll
        for (int j = 0; j < 4; ++j) {
            u16x4 v;
            v.x = t[(sq + j * 4 + 0) * 68 + d];
            v.y = t[(sq + j * 4 + 1) * 68 + d];
            v.z = t[(sq + j * 4 + 2) * 68 + d];
            v.w = t[(sq + j * 4 + 3) * 68 + d];
            *(u16x4*)(dst + sq + j * 4) = v;
        }
    }
}

// ---------------- flash attention (causal), paired q-tiles + counted vmcnt ----------------
__device__ __forceinline__ void stage_kv(const u16* __restrict__ Kg, const u16* __restrict__ Vg,
                                         u16* Kl, u16* Vl, int kv0, int tid)
{
    const int u    = tid;                         // 16B-chunk id 0..511
    const int row  = u >> 3;                      // 64 rows, 8 chunks each
    const int csrc = ((u & 7) ^ (row & 7)) * 8;   // pre-swizzled source col (elems)
    const int base = (u & ~63) * 8;               // wave-uniform LDS elem base
    gld_lds16(Kg + (size_t)(kv0 + row) * DHd + csrc, Kl + base);
    gld_lds16(Vg + (size_t)row * Ss + kv0 + csrc, Vl + base);
}

__device__ __forceinline__ void attn_tile(
    const u16* __restrict__ Kc, const u16* __restrict__ Vc, int kv0,
    int q0, int qrow, int l15, int lg, int psw,
    const bf16x8* __restrict__ bq, f32x4* __restrict__ o,
    float& m_r, float& l_r, char* __restrict__ prow)
{
    if (kv0 > q0 + 15) return;
    f32x4 s[4] = {};
    __builtin_amdgcn_s_setprio(1);
#pragma unroll
    for (int nb = 0; nb < 4; ++nb) {
        const int krow = nb * 16 + l15;
        const char* rb = (const char*)(Kc + krow * 64);
        const int sw = (krow & 7) << 4;
#pragma unroll
        for (int kf = 0; kf < 2; ++kf) {
            bf16x8 ak = *(const bf16x8*)(rb + ((kf * 64 + lg * 16) ^ sw));
            s[nb] = __builtin_amdgcn_mfma_f32_16x16x32_bf16(ak, bq[kf], s[nb], 0, 0, 0);
        }
    }
    __builtin_amdgcn_s_setprio(0);
    if (kv0 + 63 > q0) {   // diagonal region: mask kv > q
#pragma unroll
        for (int nb = 0; nb < 4; ++nb)
#pragma unroll
            for (int r = 0; r < 4; ++r)
                if (kv0 + nb * 16 + lg * 4 + r > qrow) s[nb][r] = -3e38f;
    }
    float pm = -3e38f;
#pragma unroll
    for (int nb = 0; nb < 4; ++nb)
#pragma unroll
        for (int r = 0; r < 4; ++r) pm = fmaxf(pm, s[nb][r]);
    pm = fmaxf(pm, __shfl_xor(pm, 16, 64));
    pm = fmaxf(pm, __shfl_xor(pm, 32, 64));
    // defer-max (T13): skip o-rescale while max growth <= 8
    const bool full = !__all(pm - m_r <= 8.0f);
    float mn = m_r, al = 1.0f;
    if (full) {
        mn = fmaxf(m_r, pm);
        al = __expf(m_r - mn);
#pragma unroll
        for (int nb = 0; nb < 4; ++nb)
#pragma unroll
            for (int r = 0; r < 4; ++r) o[nb][r] *= al;
    }
    float rs = 0.f;
    float p[4][4];
#pragma unroll
    for (int nb = 0; nb < 4; ++nb)
#pragma unroll
        for (int r = 0; r < 4; ++r) { p[nb][r] = __expf(s[nb][r] - mn); rs += p[nb][r]; }
    rs += __shfl_xor(rs, 16, 64);
    rs += __shfl_xor(rs, 32, 64);
    l_r = l_r * al + rs;
    m_r = mn;
#pragma unroll
    for (int nb = 0; nb < 4; ++nb) {
        const uint32_t w0 = cvtpk_bf16(p[nb][0], p[nb][1]);
        const uint32_t w1 = cvtpk_bf16(p[nb][2], p[nb][3]);
        const int c0 = (nb * 32 + lg * 8) ^ psw;
        *(uint32_t*)(prow + c0)     = w0;
        *(uint32_t*)(prow + c0 + 4) = w1;
    }
    bf16x8 pa[2];
#pragma unroll
    for (int ks = 0; ks < 2; ++ks)
        pa[ks] = *(const bf16x8*)(prow + ((ks * 64 + lg * 16) ^ psw));
    __builtin_amdgcn_s_setprio(1);
#pragma unroll
    for (int nb = 0; nb < 4; ++nb) {
        const int vrow = nb * 16 + l15;
        const char* rb = (const char*)(Vc + vrow * 64);
        const int sw = (vrow & 7) << 4;
#pragma unroll
        for (int ks = 0; ks < 2; ++ks) {
            bf16x8 bv = *(const bf16x8*)(rb + ((ks * 64 + lg * 16) ^ sw));
            o[nb] = __builtin_amdgcn_mfma_f32_16x16x32_bf16(bv, pa[ks], o[nb], 0, 0, 0);
        }
    }
    __builtin_amdgcn_s_setprio(0);
}

__global__ __launch_bounds__(512) void attn(
    const u16* __restrict__ Qb, const u16* __restrict__ Kb,
    const u16* __restrict__ Vt, u16* __restrict__ Ob)
{
    __shared__ __align__(16) u16 Kl[2][4096];
    __shared__ __align__(16) u16 Vl[2][4096];
    __shared__ __align__(16) u16 PlA[8][1024];
    __shared__ __align__(16) u16 PlB[8][1024];
    const int bh = blockIdx.y;
    const int b = bh >> 5, h = bh & 31;
    const int tid = threadIdx.x;
    const int wid = tid >> 6, lane = tid & 63;
    const int l15 = lane & 15, lg = lane >> 4;
    const int bxA = blockIdx.x, bxB = 15 - bxA;          // paired q-tiles
    const int q0A = bxA * 128 + wid * 16, q0B = bxB * 128 + wid * 16;
    const int qrowA = q0A + l15, qrowB = q0B + l15;
    char* prowA = (char*)PlA[wid] + l15 * 128;
    char* prowB = (char*)PlB[wid] + l15 * 128;
    const int psw = (l15 & 7) << 4;

    const u16* Kp = Kb + (size_t)bh * Ss * DHd;
    const u16* Vp = Vt + (size_t)bh * DHd * Ss;

    bf16x8 bqA[2], bqB[2];
    {
        const u16* QpA = Qb + ((size_t)bh * Ss + q0A) * DHd;
        const u16* QpB = Qb + ((size_t)bh * Ss + q0B) * DHd;
#pragma unroll
        for (int kf = 0; kf < 2; ++kf) {
            bqA[kf] = *(const bf16x8*)(QpA + (size_t)l15 * DHd + kf * 32 + lg * 8);
            bqB[kf] = *(const bf16x8*)(QpB + (size_t)l15 * DHd + kf * 32 + lg * 8);
        }
    }
    asm volatile("s_waitcnt vmcnt(0)" ::: "memory");   // drain Q loads: in-loop vmem = gld_lds only

    f32x4 oA[4] = {}, oB[4] = {};
    float mA = -3e38f, lA = 0.f, mB = -3e38f, lB = 0.f;
    const int nt = 2 * (bxB + 1);

    stage_kv(Kp, Vp, Kl[0], Vl[0], 0, tid);
    for (int t = 0; t < nt; ++t) {
        if (t + 1 < nt) {
            stage_kv(Kp, Vp, Kl[(t + 1) & 1], Vl[(t + 1) & 1], (t + 1) * 64, tid);
            asm volatile("s_waitcnt vmcnt(2)" ::: "memory");   // stage(t) landed (counted, no drain)
        } else {
            asm volatile("s_waitcnt vmcnt(0)" ::: "memory");
        }
        SB(); __builtin_amdgcn_s_barrier(); SB();
        const int kv0 = t * 64;
        attn_tile(Kl[t & 1], Vl[t & 1], kv0, q0A, qrowA, l15, lg, psw, bqA, oA, mA, lA, prowA);
        attn_tile(Kl[t & 1], Vl[t & 1], kv0, q0B, qrowB, l15, lg, psw, bqB, oB, mB, lB, prowB);
        SB(); __builtin_amdgcn_s_barrier(); SB();
    }

    {
        const float inv = 1.0f / lA;
        u16* orow = Ob + ((size_t)b * Ss + qrowA) * Dd + h * DHd;
#pragma unroll
        for (int nb = 0; nb < 4; ++nb) {
            u16x4 pk;
#pragma unroll
            for (int r = 0; r < 4; ++r) pk[r] = f2bf(oA[nb][r] * inv);
            *(u16x4*)(orow + nb * 16 + lg * 4) = pk;
        }
    }
    {
        const float inv = 1.0f / lB;
        u16* orow = Ob + ((size_t)b * Ss + qrowB) * Dd + h * DHd;
#pragma unroll
        for (int nb = 0; nb < 4; ++nb) {
            u16x4 pk;
#pragma unroll
            for (int r = 0; r < 4; ++r) pk[r] = f2bf(oB[nb][r] * inv);
            *(u16x4*)(orow + nb * 16 + lg * 4) = pk;
        }
    }
}

extern "C" void kernel_launch(void* const* d_in, const int* in_sizes, int n_in,
                              void* d_out, int out_size, void* d_ws, size_t ws_size,
                              hipStream_t stream)
{
    (void)in_sizes; (void)n_in; (void)out_size; (void)ws_size;
    const float* x  = (const float*)d_in[0];
    // d_in[1] = mask: causal, implemented directly
    const float* qw = (const float*)d_in[2];
    const float* qb = (const float*)d_in[3];
    const float* kw = (const float*)d_in[4];
    const float* kb = (const float*)d_in[5];
    const float* vw = (const float*)d_in[6];
    const float* vb = (const float*)d_in[7];
    const float* ow = (const float*)d_in[8];
    const float* obias = (const float*)d_in[9];

    uint8_t* ws = (uint8_t*)d_ws;
    u16* Xb  = (u16*)(ws);                 // 16 MiB [Mtok][Dd]
    u16* Wcat= (u16*)(ws + 16 * MiB);      // 24 MiB: Wq|Wk|Wv rows (6144 x 2048)
    u16* Wob = (u16*)(ws + 40 * MiB);      //  8 MiB
    u16* Qb  = (u16*)(ws + 48 * MiB);      // 16 MiB [BH][S][DH]
    u16* Kb  = (u16*)(ws + 64 * MiB);      // 16 MiB
    u16* Vb  = (u16*)(ws + 80 * MiB);      // 16 MiB
    u16* Vt  = Xb;                         // Xb dead after QKV gemms; [BH][DH][S]
    u16* Ob  = Vb;                         // Vb dead after transpose; attn out

    cvt_all<<<12288, 256, 0, stream>>>(x, qw, kw, vw, ow, Xb, Wcat, Wob);

    gemm_qkv256<<<384, 1024, 0, stream>>>(Xb, Wcat, qb, kb, vb, Qb, Kb, Vb);
    transpose_v<<<dim3(Ss / 64, 64), dim3(256), 0, stream>>>(Vb, Vt);
    attn<<<dim3(8, 64), dim3(512), 0, stream>>>(Qb, Kb, Vt, Ob);
    gemm_oproj8<<<dim3(Mtok / 128, Dd / 256), dim3(512), 0, stream>>>(
        Ob, Wob, obias, (float*)d_out);
}

// Round 16
// 231.771 us; speedup vs baseline: 1.2912x; 1.2912x over previous
//
#include <hip/hip_runtime.h>
#include <stdint.h>

#define Hh   32
#define Ss   2048
#define Dd   2048
#define DHd  64
#define Mtok 4096   // B*S
#define MiB  (1u << 20)
#define NTK  32     // K tiles of 64 in Dd

typedef unsigned short u16;
typedef u16   u16x4  __attribute__((ext_vector_type(4)));
typedef u16   u16x8  __attribute__((ext_vector_type(8)));
typedef short bf16x8 __attribute__((ext_vector_type(8)));
typedef float f32x4  __attribute__((ext_vector_type(4)));

__device__ __forceinline__ u16 f2bf(float f) {
    union { float f; uint32_t u; } v; v.f = f;
    uint32_t r = v.u + 0x7fffu + ((v.u >> 16) & 1u);   // RNE
    return (u16)(r >> 16);
}
__device__ __forceinline__ uint32_t cvtpk_bf16(float lo, float hi) {
    uint32_t r;
    asm volatile("v_cvt_pk_bf16_f32 %0, %1, %2" : "=v"(r) : "v"(lo), "v"(hi));
    return r;
}
__device__ __forceinline__ void gld_lds16(const void* g, void* l) {
    __builtin_amdgcn_global_load_lds(
        (const __attribute__((address_space(1))) uint32_t*)g,
        (__attribute__((address_space(3))) uint32_t*)l,
        16, 0, 0);
}
#define SB() __builtin_amdgcn_sched_barrier(0)

// ---------------- fused fp32 -> bf16 convert (X + 4 weights, one launch) ----------------
__global__ void cvt_all(const float* __restrict__ x,  const float* __restrict__ qw,
                        const float* __restrict__ kw, const float* __restrict__ vw,
                        const float* __restrict__ ow,
                        u16* __restrict__ Xb, u16* __restrict__ Wcat, u16* __restrict__ Wob)
{
    const size_t nX = 1u << 23, nW = 1u << 22;
    size_t i = ((size_t)blockIdx.x * 256 + threadIdx.x) * 8;
    const float* src; u16* dst; size_t off;
    if (i < nX) { src = x; dst = Xb; off = i; }
    else {
        size_t j = i - nX;
        int seg = (int)(j >> 22);
        off = j & (nW - 1);
        src = (seg == 0) ? qw : (seg == 1) ? kw : (seg == 2) ? vw : ow;
        dst = (seg == 3) ? Wob : Wcat + (size_t)seg * nW;
    }
    f32x4 a = *(const f32x4*)(src + off);
    f32x4 b = *(const f32x4*)(src + off + 4);
    u16x8 o;
    o[0] = f2bf(a[0]); o[1] = f2bf(a[1]); o[2] = f2bf(a[2]); o[3] = f2bf(a[3]);
    o[4] = f2bf(b[0]); o[5] = f2bf(b[1]); o[6] = f2bf(b[2]); o[7] = f2bf(b[3]);
    *(u16x8*)(dst + off) = o;
}

// ================= shared staging / frag helpers =================
// Unit rows of 32 elems (64B); 16B chunk c4 = ((row&1)<<2)|(col>>3), phys = c4 ^ ((row>>1)&7).
__device__ __forceinline__ void stage_unitA(const u16* __restrict__ src, u16* dst, int wid, int lane)
{   // 128 rows x 32 cols, 1 load/thread (8 waves)
    const int P = wid * 64 + lane;
    const int rp = P >> 3, c4p = P & 7, c4 = c4p ^ (rp & 7);
    const int r = rp * 2 + (c4 >> 2), c = (c4 & 3) * 8;
    gld_lds16(src + (size_t)r * Dd + c, dst + wid * 512);
}
__device__ __forceinline__ void stage_unitB(const u16* __restrict__ src, u16* dst, int wid, int lane)
{   // 256 rows x 32 cols, 2 loads/thread (8 waves)
#pragma unroll
    for (int j = 0; j < 2; ++j) {
        const int P = j * 512 + wid * 64 + lane;
        const int rp = P >> 3, c4p = P & 7, c4 = c4p ^ (rp & 7);
        const int r = rp * 2 + (c4 >> 2), c = (c4 & 3) * 8;
        gld_lds16(src + (size_t)r * Dd + c, dst + j * 4096 + wid * 512);
    }
}
__device__ __forceinline__ bf16x8 frag_read(const u16* unit, int r, int lg)
{
    const int rp = r >> 1;
    const int c4 = ((r & 1) << 2) | lg;
    const int c4p = c4 ^ (rp & 7);
    return *(const bf16x8*)(unit + rp * 64 + c4p * 8);
}

// ================= r9 2-phase core (BM=128, BN=256, 8 waves) =================
__device__ __forceinline__ void gemm2_core(const u16* __restrict__ Ab, const u16* __restrict__ Wb,
                                           u16* L, f32x4 acc[4][4],
                                           int wid, int lane, int l15, int lg, int wm, int wn)
{
    u16* const L0 = L;
    u16* const L1 = L + 24576;
    stage_unitA(Ab + 0,  L0 + 0,     wid, lane);
    stage_unitB(Wb + 0,  L0 + 8192,  wid, lane);
    stage_unitA(Ab + 32, L0 + 4096,  wid, lane);
    stage_unitB(Wb + 32, L0 + 16384, wid, lane);
    stage_unitA(Ab + 64, L1 + 0,     wid, lane);
    stage_unitB(Wb + 64, L1 + 8192,  wid, lane);
    asm volatile("s_waitcnt vmcnt(6)" ::: "memory");
    SB(); __builtin_amdgcn_s_barrier(); SB();

    const int aro = wm * 64 + l15;
    const int bro = wn * 64 + l15;
#pragma unroll 2
    for (int t = 0; t < NTK; ++t) {
        u16* const Lc = (t & 1) ? L1 : L0;
        u16* const Ln = (t & 1) ? L0 : L1;
#pragma unroll
        for (int ph = 0; ph < 2; ++ph) {
            const u16* Au = Lc + ph * 4096;
            const u16* Bu = Lc + 8192 + ph * 8192;
            bf16x8 bfr[4], a[4];
#pragma unroll
            for (int ni = 0; ni < 4; ++ni) bfr[ni] = frag_read(Bu, bro + ni * 16, lg);
#pragma unroll
            for (int mi = 0; mi < 4; ++mi) a[mi] = frag_read(Au, aro + mi * 16, lg);
            if (ph == 0) {
                if (t + 1 < NTK) {
                    stage_unitA(Ab + (t + 1) * 64 + 32, Ln + 4096,  wid, lane);
                    stage_unitB(Wb + (t + 1) * 64 + 32, Ln + 16384, wid, lane);
                }
            } else {
                if (t + 2 < NTK) {
                    stage_unitA(Ab + (t + 2) * 64, Lc + 0,    wid, lane);
                    stage_unitB(Wb + (t + 2) * 64, Lc + 8192, wid, lane);
                }
            }
            asm volatile("s_waitcnt lgkmcnt(0)" ::: "memory");
            SB();
            __builtin_amdgcn_s_setprio(1);
#pragma unroll
            for (int mi = 0; mi < 4; ++mi)
#pragma unroll
                for (int ni = 0; ni < 4; ++ni)
                    acc[mi][ni] = __builtin_amdgcn_mfma_f32_16x16x32_bf16(a[mi], bfr[ni], acc[mi][ni], 0, 0, 0);
            __builtin_amdgcn_s_setprio(0);
            const bool deep = (ph == 0) ? (t + 1 < NTK) : (t + 2 < NTK);
            if (deep) { asm volatile("s_waitcnt vmcnt(6)" ::: "memory"); }
            else      { asm volatile("s_waitcnt vmcnt(0)" ::: "memory"); }
            SB(); __builtin_amdgcn_s_barrier(); SB();
        }
    }
}

// ---------------- fused QKV projection (r9 core; V written pre-transposed) ----------------
__global__ __launch_bounds__(512) void gemm_qkv8(
    const u16* __restrict__ X, const u16* __restrict__ Wcat,
    const float* __restrict__ Bq, const float* __restrict__ Bk, const float* __restrict__ Bv,
    u16* __restrict__ Qo, u16* __restrict__ Ko, u16* __restrict__ Vt)
{
    __shared__ __align__(16) u16 L[2 * 24576];   // 96 KB
    const int tid = threadIdx.x, wid = tid >> 6, lane = tid & 63;
    const int l15 = lane & 15, lg = lane >> 4;
    const int wm = wid >> 2, wn = wid & 3;
    const int m0 = blockIdx.x * 128, n0 = blockIdx.y * 256;
    const int z = n0 >> 11;                      // 0:Q 1:K 2:V (block-uniform)

    f32x4 acc[4][4] = {};
    gemm2_core(X + (size_t)m0 * Dd, Wcat + (size_t)n0 * Dd, L, acc, wid, lane, l15, lg, wm, wn);

    if (z < 2) {
        const float* Bi = (z == 0) ? Bq : Bk;
        const float sc = (z == 0) ? 0.125f : 1.0f;
        u16* Out = (z == 0) ? Qo : Ko;
#pragma unroll
        for (int ni = 0; ni < 4; ++ni) {
            const int nn = (n0 & 2047) + wn * 64 + ni * 16 + l15;
            const float bv = Bi[nn];
            const int h = nn >> 6, dh = nn & 63;
#pragma unroll
            for (int mi = 0; mi < 4; ++mi)
#pragma unroll
                for (int r = 0; r < 4; ++r) {
                    const int m = m0 + wm * 64 + mi * 16 + lg * 4 + r;
                    const int b = m >> 11, s = m & 2047;
                    Out[(((size_t)b * Hh + h) * Ss + s) * DHd + dh] = f2bf((acc[mi][ni][r] + bv) * sc);
                }
        }
    } else {
        // V: write directly transposed [BH][DH][S] (fuses transpose_v)
#pragma unroll
        for (int ni = 0; ni < 4; ++ni) {
            const int nn = (n0 & 2047) + wn * 64 + ni * 16 + l15;
            const float bv = Bv[nn];
            const int h = nn >> 6, dh = nn & 63;
#pragma unroll
            for (int mi = 0; mi < 4; ++mi) {
                const int m = m0 + wm * 64 + mi * 16 + lg * 4;
                const int b = m >> 11, s = m & 2047;   // 4 consecutive s, same b
                u16x4 pk;
#pragma unroll
                for (int r = 0; r < 4; ++r) pk[r] = f2bf(acc[mi][ni][r] + bv);
                *(u16x4*)(Vt + (((size_t)b * Hh + h) * DHd + dh) * Ss + s) = pk;
            }
        }
    }
}

// ---------------- output projection (r9 core, fp32 out) ----------------
__global__ __launch_bounds__(512) void gemm_oproj8(
    const u16* __restrict__ A, const u16* __restrict__ W,
    const float* __restrict__ Bi, float* __restrict__ Out)
{
    __shared__ __align__(16) u16 L[2 * 24576];   // 96 KB
    const int tid = threadIdx.x, wid = tid >> 6, lane = tid & 63;
    const int l15 = lane & 15, lg = lane >> 4;
    const int wm = wid >> 2, wn = wid & 3;
    const int m0 = blockIdx.x * 128, n0 = blockIdx.y * 256;

    f32x4 acc[4][4] = {};
    gemm2_core(A + (size_t)m0 * Dd, W + (size_t)n0 * Dd, L, acc, wid, lane, l15, lg, wm, wn);

#pragma unroll
    for (int ni = 0; ni < 4; ++ni) {
        const int n = n0 + wn * 64 + ni * 16 + l15;
        const float bv = Bi[n];
#pragma unroll
        for (int mi = 0; mi < 4; ++mi)
#pragma unroll
            for (int r = 0; r < 4; ++r) {
                const int m = m0 + wm * 64 + mi * 16 + lg * 4 + r;
                Out[(size_t)m * Dd + n] = acc[mi][ni][r] + bv;
            }
    }
}

// ---------------- flash attention (causal), paired q-tiles + counted vmcnt ----------------
__device__ __forceinline__ void stage_kv(const u16* __restrict__ Kg, const u16* __restrict__ Vg,
                                         u16* Kl, u16* Vl, int kv0, int tid)
{
    const int u    = tid;                         // 16B-chunk id 0..511
    const int row  = u >> 3;                      // 64 rows, 8 chunks each
    const int csrc = ((u & 7) ^ (row & 7)) * 8;   // pre-swizzled source col (elems)
    const int base = (u & ~63) * 8;               // wave-uniform LDS elem base
    gld_lds16(Kg + (size_t)(kv0 + row) * DHd + csrc, Kl + base);
    gld_lds16(Vg + (size_t)row * Ss + kv0 + csrc, Vl + base);
}

__device__ __forceinline__ void attn_tile(
    const u16* __restrict__ Kc, const u16* __restrict__ Vc, int kv0,
    int q0, int qrow, int l15, int lg, int psw,
    const bf16x8* __restrict__ bq, f32x4* __restrict__ o,
    float& m_r, float& l_r, char* __restrict__ prow)
{
    if (kv0 > q0 + 15) return;
    f32x4 s[4] = {};
    __builtin_amdgcn_s_setprio(1);
#pragma unroll
    for (int nb = 0; nb < 4; ++nb) {
        const int krow = nb * 16 + l15;
        const char* rb = (const char*)(Kc + krow * 64);
        const int sw = (krow & 7) << 4;
#pragma unroll
        for (int kf = 0; kf < 2; ++kf) {
            bf16x8 ak = *(const bf16x8*)(rb + ((kf * 64 + lg * 16) ^ sw));
            s[nb] = __builtin_amdgcn_mfma_f32_16x16x32_bf16(ak, bq[kf], s[nb], 0, 0, 0);
        }
    }
    __builtin_amdgcn_s_setprio(0);
    if (kv0 + 63 > q0) {   // diagonal region: mask kv > q
#pragma unroll
        for (int nb = 0; nb < 4; ++nb)
#pragma unroll
            for (int r = 0; r < 4; ++r)
                if (kv0 + nb * 16 + lg * 4 + r > qrow) s[nb][r] = -3e38f;
    }
    float pm = -3e38f;
#pragma unroll
    for (int nb = 0; nb < 4; ++nb)
#pragma unroll
        for (int r = 0; r < 4; ++r) pm = fmaxf(pm, s[nb][r]);
    pm = fmaxf(pm, __shfl_xor(pm, 16, 64));
    pm = fmaxf(pm, __shfl_xor(pm, 32, 64));
    // defer-max (T13): skip o-rescale while max growth <= 8
    const bool full = !__all(pm - m_r <= 8.0f);
    float mn = m_r, al = 1.0f;
    if (full) {
        mn = fmaxf(m_r, pm);
        al = __expf(m_r - mn);
#pragma unroll
        for (int nb = 0; nb < 4; ++nb)
#pragma unroll
            for (int r = 0; r < 4; ++r) o[nb][r] *= al;
    }
    float rs = 0.f;
    float p[4][4];
#pragma unroll
    for (int nb = 0; nb < 4; ++nb)
#pragma unroll
        for (int r = 0; r < 4; ++r) { p[nb][r] = __expf(s[nb][r] - mn); rs += p[nb][r]; }
    rs += __shfl_xor(rs, 16, 64);
    rs += __shfl_xor(rs, 32, 64);
    l_r = l_r * al + rs;
    m_r = mn;
#pragma unroll
    for (int nb = 0; nb < 4; ++nb) {
        const uint32_t w0 = cvtpk_bf16(p[nb][0], p[nb][1]);
        const uint32_t w1 = cvtpk_bf16(p[nb][2], p[nb][3]);
        const int c0 = (nb * 32 + lg * 8) ^ psw;
        *(uint32_t*)(prow + c0)     = w0;
        *(uint32_t*)(prow + c0 + 4) = w1;
    }
    bf16x8 pa[2];
#pragma unroll
    for (int ks = 0; ks < 2; ++ks)
        pa[ks] = *(const bf16x8*)(prow + ((ks * 64 + lg * 16) ^ psw));
    __builtin_amdgcn_s_setprio(1);
#pragma unroll
    for (int nb = 0; nb < 4; ++nb) {
        const int vrow = nb * 16 + l15;
        const char* rb = (const char*)(Vc + vrow * 64);
        const int sw = (vrow & 7) << 4;
#pragma unroll
        for (int ks = 0; ks < 2; ++ks) {
            bf16x8 bv = *(const bf16x8*)(rb + ((ks * 64 + lg * 16) ^ sw));
            o[nb] = __builtin_amdgcn_mfma_f32_16x16x32_bf16(bv, pa[ks], o[nb], 0, 0, 0);
        }
    }
    __builtin_amdgcn_s_setprio(0);
}

__global__ __launch_bounds__(512) void attn(
    const u16* __restrict__ Qb, const u16* __restrict__ Kb,
    const u16* __restrict__ Vt, u16* __restrict__ Ob)
{
    __shared__ __align__(16) u16 Kl[2][4096];
    __shared__ __align__(16) u16 Vl[2][4096];
    __shared__ __align__(16) u16 PlA[8][1024];
    __shared__ __align__(16) u16 PlB[8][1024];
    const int bh = blockIdx.y;
    const int b = bh >> 5, h = bh & 31;
    const int tid = threadIdx.x;
    const int wid = tid >> 6, lane = tid & 63;
    const int l15 = lane & 15, lg = lane >> 4;
    const int bxA = blockIdx.x, bxB = 15 - bxA;          // paired q-tiles
    const int q0A = bxA * 128 + wid * 16, q0B = bxB * 128 + wid * 16;
    const int qrowA = q0A + l15, qrowB = q0B + l15;
    char* prowA = (char*)PlA[wid] + l15 * 128;
    char* prowB = (char*)PlB[wid] + l15 * 128;
    const int psw = (l15 & 7) << 4;

    const u16* Kp = Kb + (size_t)bh * Ss * DHd;
    const u16* Vp = Vt + (size_t)bh * DHd * Ss;

    bf16x8 bqA[2], bqB[2];
    {
        const u16* QpA = Qb + ((size_t)bh * Ss + q0A) * DHd;
        const u16* QpB = Qb + ((size_t)bh * Ss + q0B) * DHd;
#pragma unroll
        for (int kf = 0; kf < 2; ++kf) {
            bqA[kf] = *(const bf16x8*)(QpA + (size_t)l15 * DHd + kf * 32 + lg * 8);
            bqB[kf] = *(const bf16x8*)(QpB + (size_t)l15 * DHd + kf * 32 + lg * 8);
        }
    }
    asm volatile("s_waitcnt vmcnt(0)" ::: "memory");   // drain Q loads: in-loop vmem = gld_lds only

    f32x4 oA[4] = {}, oB[4] = {};
    float mA = -3e38f, lA = 0.f, mB = -3e38f, lB = 0.f;
    const int nt = 2 * (bxB + 1);

    stage_kv(Kp, Vp, Kl[0], Vl[0], 0, tid);
    for (int t = 0; t < nt; ++t) {
        if (t + 1 < nt) {
            stage_kv(Kp, Vp, Kl[(t + 1) & 1], Vl[(t + 1) & 1], (t + 1) * 64, tid);
            asm volatile("s_waitcnt vmcnt(2)" ::: "memory");   // stage(t) landed (counted, no drain)
        } else {
            asm volatile("s_waitcnt vmcnt(0)" ::: "memory");
        }
        SB(); __builtin_amdgcn_s_barrier(); SB();
        const int kv0 = t * 64;
        attn_tile(Kl[t & 1], Vl[t & 1], kv0, q0A, qrowA, l15, lg, psw, bqA, oA, mA, lA, prowA);
        attn_tile(Kl[t & 1], Vl[t & 1], kv0, q0B, qrowB, l15, lg, psw, bqB, oB, mB, lB, prowB);
        SB(); __builtin_amdgcn_s_barrier(); SB();
    }

    {
        const float inv = 1.0f / lA;
        u16* orow = Ob + ((size_t)b * Ss + qrowA) * Dd + h * DHd;
#pragma unroll
        for (int nb = 0; nb < 4; ++nb) {
            u16x4 pk;
#pragma unroll
            for (int r = 0; r < 4; ++r) pk[r] = f2bf(oA[nb][r] * inv);
            *(u16x4*)(orow + nb * 16 + lg * 4) = pk;
        }
    }
    {
        const float inv = 1.0f / lB;
        u16* orow = Ob + ((size_t)b * Ss + qrowB) * Dd + h * DHd;
#pragma unroll
        for (int nb = 0; nb < 4; ++nb) {
            u16x4 pk;
#pragma unroll
            for (int r = 0; r < 4; ++r) pk[r] = f2bf(oB[nb][r] * inv);
            *(u16x4*)(orow + nb * 16 + lg * 4) = pk;
        }
    }
}

extern "C" void kernel_launch(void* const* d_in, const int* in_sizes, int n_in,
                              void* d_out, int out_size, void* d_ws, size_t ws_size,
                              hipStream_t stream)
{
    (void)in_sizes; (void)n_in; (void)out_size; (void)ws_size;
    const float* x  = (const float*)d_in[0];
    // d_in[1] = mask: causal, implemented directly
    const float* qw = (const float*)d_in[2];
    const float* qb = (const float*)d_in[3];
    const float* kw = (const float*)d_in[4];
    const float* kb = (const float*)d_in[5];
    const float* vw = (const float*)d_in[6];
    const float* vb = (const float*)d_in[7];
    const float* ow = (const float*)d_in[8];
    const float* obias = (const float*)d_in[9];

    uint8_t* ws = (uint8_t*)d_ws;
    u16* Xb  = (u16*)(ws);                 // 16 MiB [Mtok][Dd]
    u16* Wcat= (u16*)(ws + 16 * MiB);      // 24 MiB: Wq|Wk|Wv rows (6144 x 2048); dead after qkv
    u16* Wob = (u16*)(ws + 40 * MiB);      //  8 MiB
    u16* Qb  = (u16*)(ws + 48 * MiB);      // 16 MiB [BH][S][DH]
    u16* Kb  = (u16*)(ws + 64 * MiB);      // 16 MiB
    u16* Vt  = (u16*)(ws + 80 * MiB);      // 16 MiB [BH][DH][S] (written pre-transposed)
    u16* Ob  = Wcat;                       // attn out reuses dead Wcat slot

    cvt_all<<<12288, 256, 0, stream>>>(x, qw, kw, vw, ow, Xb, Wcat, Wob);

    gemm_qkv8<<<dim3(Mtok / 128, 6144 / 256), dim3(512), 0, stream>>>(
        Xb, Wcat, qb, kb, vb, Qb, Kb, Vt);
    attn<<<dim3(8, 64), dim3(512), 0, stream>>>(Qb, Kb, Vt, Ob);
    gemm_oproj8<<<dim3(Mtok / 128, Dd / 256), dim3(512), 0, stream>>>(
        Ob, Wob, obias, (float*)d_out);
}